// Round 1
// baseline (895.412 us; speedup 1.0000x reference)
//
#include <hip/hip_runtime.h>
#include <hip/hip_bf16.h>
#include <math.h>

// Problem constants
#define B_   32
#define SX_  512
#define SM_  4096
#define D_   256
#define TOPK_ 5

// GEMM tiling
#define BM 128
#define BN 128
#define BK 32

// ---------------------------------------------------------------------------
// Kernel 1: inverse L2 norm per row of a [nrows, 256] fp32 matrix.
// One wave (64 lanes) per row, float4 per lane.
// ---------------------------------------------------------------------------
__global__ __launch_bounds__(256) void invnorm_kernel(
    const float* __restrict__ in, float* __restrict__ out, int nrows)
{
    int row  = blockIdx.x * 4 + (threadIdx.x >> 6);
    int lane = threadIdx.x & 63;
    if (row >= nrows) return;
    const float4 v = *(const float4*)(in + (size_t)row * D_ + lane * 4);
    float s = v.x * v.x + v.y * v.y + v.z * v.z + v.w * v.w;
    #pragma unroll
    for (int off = 32; off > 0; off >>= 1) s += __shfl_xor(s, off);
    if (lane == 0) out[row] = 1.0f / sqrtf(s);
}

// ---------------------------------------------------------------------------
// Kernel 2: fused GEMM + row-max.
// Per (b, m-tile): rowmax[b][m] = invnm[b][m] * max_s ( dot(mem[b][m], x[b][s]) * invnx[b][s] )
// 256 threads, each computes an 8x8 register tile; 128x128 block tile, BK=32.
// Running max over s kept in registers; sim matrix never materialized.
// ---------------------------------------------------------------------------
__global__ __launch_bounds__(256, 4) void gemm_max_kernel(
    const float* __restrict__ x,      // [B, SX, D]
    const float* __restrict__ mem,    // [B, SM, D]
    const float* __restrict__ invnx,  // [B*SX]
    const float* __restrict__ invnm,  // [B*SM]
    float* __restrict__ rowmax)       // [B*SM]
{
    __shared__ union {
        struct { float As[BK][BM]; float Bs[BK][BN]; } ab;  // 32 KB
        float maxbuf[BM][17];                               // 8.7 KB (reused at end)
    } u;
    __shared__ float snorm[BN];

    const int b   = blockIdx.y;
    const int m0  = blockIdx.x * BM;
    const int tid = threadIdx.x;
    const int ti  = tid >> 4;        // 0..15 : m sub-block
    const int tj  = tid & 15;        // 0..15 : s sub-block

    const float* memb = mem + ((size_t)b * SM_ + m0) * D_;
    const float* xb   = x   + (size_t)b * SX_ * D_;

    // staging decomposition: thread -> (row, 4-float col) of a [128][32] chunk
    const int sr = tid >> 3;         // 0..31
    const int sc = (tid & 7) * 4;    // 0,4,...,28

    float rowmax8[8];
    #pragma unroll
    for (int i = 0; i < 8; ++i) rowmax8[i] = -INFINITY;

    #pragma unroll 1
    for (int s0 = 0; s0 < SX_; s0 += BN) {
        __syncthreads();   // guard snorm/LDS against previous iteration readers
        if (tid < BN) snorm[tid] = invnx[b * SX_ + s0 + tid];

        float acc[8][8];
        #pragma unroll
        for (int i = 0; i < 8; ++i)
            #pragma unroll
            for (int j = 0; j < 8; ++j) acc[i][j] = 0.0f;

        #pragma unroll 1
        for (int k0 = 0; k0 < D_; k0 += BK) {
            __syncthreads();
            // stage A (mem tile, transposed to As[k][m])
            #pragma unroll
            for (int p = 0; p < 4; ++p) {
                int r = sr + p * 32;
                const float4 v = *(const float4*)(memb + (size_t)r * D_ + k0 + sc);
                u.ab.As[sc + 0][r] = v.x;
                u.ab.As[sc + 1][r] = v.y;
                u.ab.As[sc + 2][r] = v.z;
                u.ab.As[sc + 3][r] = v.w;
            }
            // stage B (x tile, transposed to Bs[k][s])
            #pragma unroll
            for (int p = 0; p < 4; ++p) {
                int r = sr + p * 32;
                const float4 v = *(const float4*)(xb + (size_t)(s0 + r) * D_ + k0 + sc);
                u.ab.Bs[sc + 0][r] = v.x;
                u.ab.Bs[sc + 1][r] = v.y;
                u.ab.Bs[sc + 2][r] = v.z;
                u.ab.Bs[sc + 3][r] = v.w;
            }
            __syncthreads();

            #pragma unroll 8
            for (int k = 0; k < BK; ++k) {
                const float4 a0 = *(const float4*)&u.ab.As[k][ti * 8];
                const float4 a1 = *(const float4*)&u.ab.As[k][ti * 8 + 4];
                const float4 b0 = *(const float4*)&u.ab.Bs[k][tj * 8];
                const float4 b1 = *(const float4*)&u.ab.Bs[k][tj * 8 + 4];
                const float a[8]  = {a0.x, a0.y, a0.z, a0.w, a1.x, a1.y, a1.z, a1.w};
                const float bb[8] = {b0.x, b0.y, b0.z, b0.w, b1.x, b1.y, b1.z, b1.w};
                #pragma unroll
                for (int i = 0; i < 8; ++i)
                    #pragma unroll
                    for (int j = 0; j < 8; ++j)
                        acc[i][j] = fmaf(a[i], bb[j], acc[i][j]);
            }
        }

        // epilogue: scale by query inv-norm, fold into running row max
        #pragma unroll
        for (int j = 0; j < 8; ++j) {
            const float sn = snorm[tj * 8 + j];
            #pragma unroll
            for (int i = 0; i < 8; ++i)
                rowmax8[i] = fmaxf(rowmax8[i], acc[i][j] * sn);
        }
    }

    // cross-thread max reduce over the 16 s sub-blocks
    __syncthreads();
    #pragma unroll
    for (int i = 0; i < 8; ++i) u.maxbuf[ti * 8 + i][tj] = rowmax8[i];
    __syncthreads();
    if (tid < BM) {
        float v = u.maxbuf[tid][0];
        #pragma unroll
        for (int j = 1; j < 16; ++j) v = fmaxf(v, u.maxbuf[tid][j]);
        rowmax[(size_t)b * SM_ + m0 + tid] = v * invnm[b * SM_ + m0 + tid];
    }
}

// ---------------------------------------------------------------------------
// Kernel 3: per batch, top-5 (tie -> lower index, matching lax.top_k) over
// rowmax[b][0..4095], then gather the 5 memory rows and write indices.
// One block per batch element.
// ---------------------------------------------------------------------------
__global__ __launch_bounds__(256) void top5_gather_kernel(
    const float* __restrict__ rowmax,  // [B*SM]
    const float* __restrict__ mem,     // [B, SM, D]
    float* __restrict__ out)           // [5*B*D + B*5] as fp32
{
    __shared__ float vals[SM_];
    __shared__ float rv[256];
    __shared__ int   ri[256];
    __shared__ int   topidx[TOPK_];

    const int b = blockIdx.x, tid = threadIdx.x;
    const float* rm = rowmax + (size_t)b * SM_;
    for (int i = tid; i < SM_; i += 256) vals[i] = rm[i];
    __syncthreads();

    for (int k = 0; k < TOPK_; ++k) {
        float bestv = -INFINITY;
        int   besti = SM_;
        #pragma unroll
        for (int uu = 0; uu < SM_ / 256; ++uu) {
            const int idx = tid * (SM_ / 256) + uu;   // ascending -> strict > keeps lowest idx
            const float v = vals[idx];
            if (v > bestv) { bestv = v; besti = idx; }
        }
        rv[tid] = bestv; ri[tid] = besti;
        __syncthreads();
        for (int off = 128; off > 0; off >>= 1) {
            if (tid < off) {
                const float ov = rv[tid + off]; const int oi = ri[tid + off];
                if (ov > rv[tid] || (ov == rv[tid] && oi < ri[tid])) { rv[tid] = ov; ri[tid] = oi; }
            }
            __syncthreads();
        }
        if (tid == 0) { topidx[k] = ri[0]; vals[ri[0]] = -INFINITY; }
        __syncthreads();
    }

    // gather: out_k[b][d] = mem[b][topidx[k]][d], d = tid (256 threads = D)
    const float* memb = mem + (size_t)b * SM_ * D_;
    #pragma unroll
    for (int k = 0; k < TOPK_; ++k)
        out[(size_t)k * B_ * D_ + (size_t)b * D_ + tid] = memb[(size_t)topidx[k] * D_ + tid];
    // indices as float, appended after the 5 gathered outputs
    if (tid < TOPK_) out[(size_t)TOPK_ * B_ * D_ + b * TOPK_ + tid] = (float)topidx[tid];
}

// ---------------------------------------------------------------------------
extern "C" void kernel_launch(void* const* d_in, const int* in_sizes, int n_in,
                              void* d_out, int out_size, void* d_ws, size_t ws_size,
                              hipStream_t stream)
{
    const float* x   = (const float*)d_in[0];   // [32, 512, 256]
    const float* mem = (const float*)d_in[1];   // [32, 4096, 256]
    float* out = (float*)d_out;

    float* invnx  = (float*)d_ws;               // 32*512
    float* invnm  = invnx + B_ * SX_;           // 32*4096
    float* rowmax = invnm + B_ * SM_;           // 32*4096

    invnorm_kernel<<<(B_ * SX_) / 4, 256, 0, stream>>>(x, invnx, B_ * SX_);
    invnorm_kernel<<<(B_ * SM_) / 4, 256, 0, stream>>>(mem, invnm, B_ * SM_);

    dim3 grid(SM_ / BM, B_);
    gemm_max_kernel<<<grid, 256, 0, stream>>>(x, mem, invnx, invnm, rowmax);

    top5_gather_kernel<<<B_, 256, 0, stream>>>(rowmax, mem, out);
}

// Round 3
// 603.473 us; speedup vs baseline: 1.4838x; 1.4838x over previous
//
#include <hip/hip_runtime.h>
#include <hip/hip_bf16.h>
#include <math.h>

// Problem constants
#define B_   32
#define SX_  512
#define SM_  4096
#define D_   256
#define TOPK_ 5

// GEMM tiling
#define BM 128
#define BN 128
#define BK 32

// ---------------------------------------------------------------------------
// Kernel 1: inverse L2 norm per row of a [nrows, 256] fp32 matrix.
// One wave (64 lanes) per row, float4 per lane.
// ---------------------------------------------------------------------------
__global__ __launch_bounds__(256) void invnorm_kernel(
    const float* __restrict__ in, float* __restrict__ out, int nrows)
{
    int row  = blockIdx.x * 4 + (threadIdx.x >> 6);
    int lane = threadIdx.x & 63;
    if (row >= nrows) return;
    const float4 v = *(const float4*)(in + (size_t)row * D_ + lane * 4);
    float s = v.x * v.x + v.y * v.y + v.z * v.z + v.w * v.w;
    #pragma unroll
    for (int off = 32; off > 0; off >>= 1) s += __shfl_xor(s, off);
    if (lane == 0) out[row] = 1.0f / sqrtf(s);
}

// ---------------------------------------------------------------------------
// Kernel 2: fused GEMM + row-max, LDS-conflict-free version.
//
// LDS layout: As[k][m'] / Bs[k][s'] with XOR swizzle m' = m ^ (k & ~3).
//   - staging writes: bank = (r ^ sc) % 32, bijective over (sr, sc/4) -> 2-way (free)
//   - FMA reads: float4 at m = t*4 ^ (k&28) and +64 -> chunks cover all 8 bank
//     quads evenly (the b128 hardware minimum)
// Per-thread 8x8 register tile split lo4/hi4 at +64.
// ---------------------------------------------------------------------------
__global__ __launch_bounds__(256, 4) void gemm_max_kernel(
    const float* __restrict__ x,      // [B, SX, D]
    const float* __restrict__ mem,    // [B, SM, D]
    const float* __restrict__ invnx,  // [B*SX]
    const float* __restrict__ invnm,  // [B*SM]
    float* __restrict__ rowmax)       // [B*SM]
{
    __shared__ union {
        struct { float As[BK][BM]; float Bs[BK][BN]; } ab;  // 32 KB
        float maxbuf[BM][17];                               // reused for final reduce
    } u;

    const int b   = blockIdx.y;
    const int m0  = blockIdx.x * BM;
    const int tid = threadIdx.x;
    const int ti4 = (tid >> 4) * 4;   // row sub-block base (0..60)
    const int tj4 = (tid & 15) * 4;   // col sub-block base (0..60)

    const float* memb = mem + ((size_t)b * SM_ + m0) * D_;
    const float* xb   = x   + (size_t)b * SX_ * D_;

    // staging decomposition: thread -> (row sr(+32p), 4-float col sc) of [128][32]
    const int sr = tid >> 3;          // 0..31
    const int sc = (tid & 7) * 4;     // 0,4,...,28

    float rowmax8[8];
    #pragma unroll
    for (int i = 0; i < 8; ++i) rowmax8[i] = -INFINITY;

    #pragma unroll 1
    for (int s0 = 0; s0 < SX_; s0 += BN) {
        float acc[8][8];
        #pragma unroll
        for (int i = 0; i < 8; ++i)
            #pragma unroll
            for (int j = 0; j < 8; ++j) acc[i][j] = 0.0f;

        #pragma unroll 1
        for (int k0 = 0; k0 < D_; k0 += BK) {
            __syncthreads();   // previous tile's readers done
            // stage A and B, transposed + swizzled: element (row r, col k=sc+i)
            // stored at [k][r ^ sc]  (swizzle const = k & ~3 = sc for i<4)
            #pragma unroll
            for (int p = 0; p < 4; ++p) {
                const int r  = sr + p * 32;
                const int mw = r ^ sc;
                const float4 va = *(const float4*)(memb + (size_t)r * D_ + k0 + sc);
                u.ab.As[sc + 0][mw] = va.x;
                u.ab.As[sc + 1][mw] = va.y;
                u.ab.As[sc + 2][mw] = va.z;
                u.ab.As[sc + 3][mw] = va.w;
                const float4 vb = *(const float4*)(xb + (size_t)(s0 + r) * D_ + k0 + sc);
                u.ab.Bs[sc + 0][mw] = vb.x;
                u.ab.Bs[sc + 1][mw] = vb.y;
                u.ab.Bs[sc + 2][mw] = vb.z;
                u.ab.Bs[sc + 3][mw] = vb.w;
            }
            __syncthreads();

            #pragma unroll
            for (int g = 0; g < 8; ++g) {
                const int xo = g << 2;                         // k & 28
                const float* pa = &u.ab.As[0][ti4 ^ xo];
                const float* pb = &u.ab.Bs[0][tj4 ^ xo];
                #pragma unroll
                for (int q = 0; q < 4; ++q) {
                    const int k = 4 * g + q;
                    const float4 a0 = *(const float4*)(pa + k * BM);
                    const float4 a1 = *(const float4*)(pa + k * BM + 64);
                    const float4 b0 = *(const float4*)(pb + k * BN);
                    const float4 b1 = *(const float4*)(pb + k * BN + 64);
                    const float a[8]  = {a0.x, a0.y, a0.z, a0.w, a1.x, a1.y, a1.z, a1.w};
                    const float bb[8] = {b0.x, b0.y, b0.z, b0.w, b1.x, b1.y, b1.z, b1.w};
                    #pragma unroll
                    for (int i = 0; i < 8; ++i)
                        #pragma unroll
                        for (int j = 0; j < 8; ++j)
                            acc[i][j] = fmaf(a[i], bb[j], acc[i][j]);
                }
            }
        }

        // epilogue: scale by query inv-norms (L2-hot direct loads), fold into max
        const float* nx = invnx + b * SX_ + s0;
        const float4 sn0 = *(const float4*)(nx + tj4);
        const float4 sn1 = *(const float4*)(nx + tj4 + 64);
        const float sn[8] = {sn0.x, sn0.y, sn0.z, sn0.w, sn1.x, sn1.y, sn1.z, sn1.w};
        #pragma unroll
        for (int j = 0; j < 8; ++j) {
            #pragma unroll
            for (int i = 0; i < 8; ++i)
                rowmax8[i] = fmaxf(rowmax8[i], acc[i][j] * sn[j]);
        }
    }

    // cross-thread max reduce over the 16 col sub-blocks
    __syncthreads();
    #pragma unroll
    for (int i = 0; i < 8; ++i) {
        const int m = ti4 + (i & 3) + (i >> 2) * 64;   // this thread's row i
        u.maxbuf[m][tid & 15] = rowmax8[i];
    }
    __syncthreads();
    if (tid < BM) {
        float v = u.maxbuf[tid][0];
        #pragma unroll
        for (int j = 1; j < 16; ++j) v = fmaxf(v, u.maxbuf[tid][j]);
        rowmax[(size_t)b * SM_ + m0 + tid] = v * invnm[b * SM_ + m0 + tid];
    }
}

// ---------------------------------------------------------------------------
// Kernel 3: per batch, top-5 (tie -> lower index, matching lax.top_k) over
// rowmax[b][0..4095], then gather the 5 memory rows and write indices.
// One block per batch element.
// ---------------------------------------------------------------------------
__global__ __launch_bounds__(256) void top5_gather_kernel(
    const float* __restrict__ rowmax,  // [B*SM]
    const float* __restrict__ mem,     // [B, SM, D]
    float* __restrict__ out)           // [5*B*D + B*5] as fp32
{
    __shared__ float vals[SM_];
    __shared__ float rv[256];
    __shared__ int   ri[256];
    __shared__ int   topidx[TOPK_];

    const int b = blockIdx.x, tid = threadIdx.x;
    const float* rm = rowmax + (size_t)b * SM_;
    for (int i = tid; i < SM_; i += 256) vals[i] = rm[i];
    __syncthreads();

    for (int k = 0; k < TOPK_; ++k) {
        float bestv = -INFINITY;
        int   besti = SM_;
        #pragma unroll
        for (int uu = 0; uu < SM_ / 256; ++uu) {
            const int idx = tid * (SM_ / 256) + uu;   // ascending -> strict > keeps lowest idx
            const float v = vals[idx];
            if (v > bestv) { bestv = v; besti = idx; }
        }
        rv[tid] = bestv; ri[tid] = besti;
        __syncthreads();
        for (int off = 128; off > 0; off >>= 1) {
            if (tid < off) {
                const float ov = rv[tid + off]; const int oi = ri[tid + off];
                if (ov > rv[tid] || (ov == rv[tid] && oi < ri[tid])) { rv[tid] = ov; ri[tid] = oi; }
            }
            __syncthreads();
        }
        if (tid == 0) { topidx[k] = ri[0]; vals[ri[0]] = -INFINITY; }
        __syncthreads();
    }

    // gather: out_k[b][d] = mem[b][topidx[k]][d], d = tid (256 threads = D)
    const float* memb = mem + (size_t)b * SM_ * D_;
    #pragma unroll
    for (int k = 0; k < TOPK_; ++k)
        out[(size_t)k * B_ * D_ + (size_t)b * D_ + tid] = memb[(size_t)topidx[k] * D_ + tid];
    // indices as float, appended after the 5 gathered outputs
    if (tid < TOPK_) out[(size_t)TOPK_ * B_ * D_ + b * TOPK_ + tid] = (float)topidx[tid];
}

// ---------------------------------------------------------------------------
extern "C" void kernel_launch(void* const* d_in, const int* in_sizes, int n_in,
                              void* d_out, int out_size, void* d_ws, size_t ws_size,
                              hipStream_t stream)
{
    const float* x   = (const float*)d_in[0];   // [32, 512, 256]
    const float* mem = (const float*)d_in[1];   // [32, 4096, 256]
    float* out = (float*)d_out;

    float* invnx  = (float*)d_ws;               // 32*512
    float* invnm  = invnx + B_ * SX_;           // 32*4096
    float* rowmax = invnm + B_ * SM_;           // 32*4096

    invnorm_kernel<<<(B_ * SX_) / 4, 256, 0, stream>>>(x, invnx, B_ * SX_);
    invnorm_kernel<<<(B_ * SM_) / 4, 256, 0, stream>>>(mem, invnm, B_ * SM_);

    dim3 grid(SM_ / BM, B_);
    gemm_max_kernel<<<grid, 256, 0, stream>>>(x, mem, invnx, invnm, rowmax);

    top5_gather_kernel<<<B_, 256, 0, stream>>>(rowmax, mem, out);
}

// Round 4
// 354.786 us; speedup vs baseline: 2.5238x; 1.7009x over previous
//
#include <hip/hip_runtime.h>
#include <hip/hip_bf16.h>
#include <math.h>

// Problem constants
#define B_   32
#define SX_  512
#define SM_  4096
#define D_   256
#define TOPK_ 5

// GEMM tiling
#define BM 128
#define BN 128
#define BK 32

typedef _Float16 half8 __attribute__((ext_vector_type(8)));
typedef _Float16 half4 __attribute__((ext_vector_type(4)));
typedef float    f32x4 __attribute__((ext_vector_type(4)));

// ---------------------------------------------------------------------------
// Kernel 1: inverse L2 norm per row of a [nrows, 256] fp32 matrix.
// ---------------------------------------------------------------------------
__global__ __launch_bounds__(256) void invnorm_kernel(
    const float* __restrict__ in, float* __restrict__ out, int nrows)
{
    int row  = blockIdx.x * 4 + (threadIdx.x >> 6);
    int lane = threadIdx.x & 63;
    if (row >= nrows) return;
    const float4 v = *(const float4*)(in + (size_t)row * D_ + lane * 4);
    float s = v.x * v.x + v.y * v.y + v.z * v.z + v.w * v.w;
    #pragma unroll
    for (int off = 32; off > 0; off >>= 1) s += __shfl_xor(s, off);
    if (lane == 0) out[row] = 1.0f / sqrtf(s);
}

// ---------------------------------------------------------------------------
// Kernel 2: fused GEMM + row-max via split-fp16 MFMA.
//   dot_f32(a,b) ~= mfma(ah,bh) + mfma(ah,bl) + mfma(al,bh), fp32 accum.
//   Error ~2^-24 per term -> cosine error ~1e-8 << top-5 gaps (~1e-3).
// Block 128x128, BK=32, 4 waves, each wave a 64x64 tile of 4x4 mfma 16x16x32.
// LDS: Ah/Al/Bh/Bl [128][32] fp16, chunk-XOR swizzle:
//   off(row,k) = row*32 + (((k>>3) ^ ((row>>1)&3))<<3 | (k&7))
//   -> b128 fragment reads hit each 16B bank-group evenly (hw floor),
//      b64 staging writes 4-way (hw floor).
// C/D layout (m89-verified): col = lane&15 (s), row = (lane>>4)*4 + reg (m).
// ---------------------------------------------------------------------------
__device__ __forceinline__ int lds_off(int row, int k) {
    return row * 32 + ((((k >> 3) ^ ((row >> 1) & 3)) << 3) | (k & 7));
}

__global__ __launch_bounds__(256) void gemm_max_kernel(
    const float* __restrict__ x,      // [B, SX, D]
    const float* __restrict__ mem,    // [B, SM, D]
    const float* __restrict__ invnx,  // [B*SX]
    const float* __restrict__ invnm,  // [B*SM]
    float* __restrict__ rowmax)       // [B*SM]
{
    __shared__ union __align__(16) {
        _Float16 t[4][BM * BK];      // Ah, Al, Bh, Bl : 32 KB
        float red[2][BM];            // reused for final cross-wave max
    } u;

    const int b   = blockIdx.y;
    const int m0  = blockIdx.x * BM;
    const int tid = threadIdx.x;
    const int wid = tid >> 6, lane = tid & 63;
    const int wm  = (wid >> 1) * 64;   // wave m-origin in block
    const int wsj = (wid & 1) * 64;    // wave s-origin in s-tile

    const float* memb = mem + ((size_t)b * SM_ + m0) * D_;
    const float* xb   = x   + (size_t)b * SX_ * D_;

    // staging: thread -> rows sr+32p (p=0..3), cols sc..sc+3
    const int sr = tid >> 3;           // 0..31
    const int sc = (tid & 7) * 4;      // 0,4,...,28

    // fragment coords
    const int fm  = lane & 15;         // row/col within 16-tile
    const int fkc = lane >> 4;         // k-chunk-of-8 (0..3)

    float part[4][4];                  // running row-max [mt][reg]
    #pragma unroll
    for (int i = 0; i < 4; ++i)
        #pragma unroll
        for (int j = 0; j < 4; ++j) part[i][j] = -INFINITY;

    #pragma unroll 1
    for (int s0 = 0; s0 < SX_; s0 += BN) {
        f32x4 acc[4][4];               // [mt][st]
        #pragma unroll
        for (int i = 0; i < 4; ++i)
            #pragma unroll
            for (int j = 0; j < 4; ++j) acc[i][j] = (f32x4){0.f, 0.f, 0.f, 0.f};

        // prefetch chunk 0 into registers
        float4 ra[4], rb[4];
        #pragma unroll
        for (int p = 0; p < 4; ++p) {
            const int r = sr + 32 * p;
            ra[p] = *(const float4*)(memb + (size_t)r * D_ + sc);
            rb[p] = *(const float4*)(xb + (size_t)(s0 + r) * D_ + sc);
        }

        #pragma unroll 1
        for (int k0 = 0; k0 < D_; k0 += BK) {
            __syncthreads();   // previous chunk's readers done
            // convert fp32 -> (hi, lo) fp16 and write swizzled LDS
            #pragma unroll
            for (int p = 0; p < 4; ++p) {
                const int r  = sr + 32 * p;
                const int oa = lds_off(r, sc);
                half4 hi, lo;
                hi[0] = (_Float16)ra[p].x; lo[0] = (_Float16)(ra[p].x - (float)hi[0]);
                hi[1] = (_Float16)ra[p].y; lo[1] = (_Float16)(ra[p].y - (float)hi[1]);
                hi[2] = (_Float16)ra[p].z; lo[2] = (_Float16)(ra[p].z - (float)hi[2]);
                hi[3] = (_Float16)ra[p].w; lo[3] = (_Float16)(ra[p].w - (float)hi[3]);
                *(half4*)&u.t[0][oa] = hi;
                *(half4*)&u.t[1][oa] = lo;
                hi[0] = (_Float16)rb[p].x; lo[0] = (_Float16)(rb[p].x - (float)hi[0]);
                hi[1] = (_Float16)rb[p].y; lo[1] = (_Float16)(rb[p].y - (float)hi[1]);
                hi[2] = (_Float16)rb[p].z; lo[2] = (_Float16)(rb[p].z - (float)hi[2]);
                hi[3] = (_Float16)rb[p].w; lo[3] = (_Float16)(rb[p].w - (float)hi[3]);
                *(half4*)&u.t[2][oa] = hi;
                *(half4*)&u.t[3][oa] = lo;
            }
            __syncthreads();

            // prefetch next chunk (stays in flight under the MFMA phase)
            if (k0 + BK < D_) {
                #pragma unroll
                for (int p = 0; p < 4; ++p) {
                    const int r = sr + 32 * p;
                    ra[p] = *(const float4*)(memb + (size_t)r * D_ + k0 + BK + sc);
                    rb[p] = *(const float4*)(xb + (size_t)(s0 + r) * D_ + k0 + BK + sc);
                }
            }

            // A fragments for this wave's 4 m-tiles
            half8 ah[4], al[4];
            #pragma unroll
            for (int mt = 0; mt < 4; ++mt) {
                const int o = lds_off(wm + mt * 16 + fm, fkc * 8);
                ah[mt] = *(const half8*)&u.t[0][o];
                al[mt] = *(const half8*)&u.t[1][o];
            }
            #pragma unroll
            for (int st = 0; st < 4; ++st) {
                const int o = lds_off(wsj + st * 16 + fm, fkc * 8);
                const half8 bh = *(const half8*)&u.t[2][o];
                const half8 bl = *(const half8*)&u.t[3][o];
                #pragma unroll
                for (int mt = 0; mt < 4; ++mt)
                    acc[mt][st] = __builtin_amdgcn_mfma_f32_16x16x32_f16(ah[mt], bh, acc[mt][st], 0, 0, 0);
                #pragma unroll
                for (int mt = 0; mt < 4; ++mt)
                    acc[mt][st] = __builtin_amdgcn_mfma_f32_16x16x32_f16(ah[mt], bl, acc[mt][st], 0, 0, 0);
                #pragma unroll
                for (int mt = 0; mt < 4; ++mt)
                    acc[mt][st] = __builtin_amdgcn_mfma_f32_16x16x32_f16(al[mt], bh, acc[mt][st], 0, 0, 0);
            }
        }

        // epilogue: scale by query inv-norm, fold into running row-max
        #pragma unroll
        for (int st = 0; st < 4; ++st) {
            const float sn = invnx[b * SX_ + s0 + wsj + st * 16 + fm];
            #pragma unroll
            for (int mt = 0; mt < 4; ++mt)
                #pragma unroll
                for (int j = 0; j < 4; ++j)
                    part[mt][j] = fmaxf(part[mt][j], acc[mt][st][j] * sn);
        }
    }

    // reduce across the 16 s-lanes (fm = lane&15)
    #pragma unroll
    for (int off = 1; off < 16; off <<= 1)
        #pragma unroll
        for (int mt = 0; mt < 4; ++mt)
            #pragma unroll
            for (int j = 0; j < 4; ++j)
                part[mt][j] = fmaxf(part[mt][j], __shfl_xor(part[mt][j], off));

    __syncthreads();   // all MFMA LDS reads done before aliasing as red buffer
    if (fm == 0) {
        #pragma unroll
        for (int mt = 0; mt < 4; ++mt)
            #pragma unroll
            for (int j = 0; j < 4; ++j)
                u.red[wid & 1][wm + mt * 16 + fkc * 4 + j] = part[mt][j];
    }
    __syncthreads();
    if (tid < BM) {
        const float v = fmaxf(u.red[0][tid], u.red[1][tid]);
        rowmax[(size_t)b * SM_ + m0 + tid] = v * invnm[b * SM_ + m0 + tid];
    }
}

// ---------------------------------------------------------------------------
// Kernel 3: per batch top-5 (tie -> lower index) + gather + index write.
// ---------------------------------------------------------------------------
__global__ __launch_bounds__(256) void top5_gather_kernel(
    const float* __restrict__ rowmax,  // [B*SM]
    const float* __restrict__ mem,     // [B, SM, D]
    float* __restrict__ out)           // [5*B*D + B*5] as fp32
{
    __shared__ float vals[SM_];
    __shared__ float rv[256];
    __shared__ int   ri[256];
    __shared__ int   topidx[TOPK_];

    const int b = blockIdx.x, tid = threadIdx.x;
    const float* rm = rowmax + (size_t)b * SM_;
    for (int i = tid; i < SM_; i += 256) vals[i] = rm[i];
    __syncthreads();

    for (int k = 0; k < TOPK_; ++k) {
        float bestv = -INFINITY;
        int   besti = SM_;
        #pragma unroll
        for (int uu = 0; uu < SM_ / 256; ++uu) {
            const int idx = tid * (SM_ / 256) + uu;   // ascending -> strict > keeps lowest idx
            const float v = vals[idx];
            if (v > bestv) { bestv = v; besti = idx; }
        }
        rv[tid] = bestv; ri[tid] = besti;
        __syncthreads();
        for (int off = 128; off > 0; off >>= 1) {
            if (tid < off) {
                const float ov = rv[tid + off]; const int oi = ri[tid + off];
                if (ov > rv[tid] || (ov == rv[tid] && oi < ri[tid])) { rv[tid] = ov; ri[tid] = oi; }
            }
            __syncthreads();
        }
        if (tid == 0) { topidx[k] = ri[0]; vals[ri[0]] = -INFINITY; }
        __syncthreads();
    }

    const float* memb = mem + (size_t)b * SM_ * D_;
    #pragma unroll
    for (int k = 0; k < TOPK_; ++k)
        out[(size_t)k * B_ * D_ + (size_t)b * D_ + tid] = memb[(size_t)topidx[k] * D_ + tid];
    if (tid < TOPK_) out[(size_t)TOPK_ * B_ * D_ + b * TOPK_ + tid] = (float)topidx[tid];
}

// ---------------------------------------------------------------------------
extern "C" void kernel_launch(void* const* d_in, const int* in_sizes, int n_in,
                              void* d_out, int out_size, void* d_ws, size_t ws_size,
                              hipStream_t stream)
{
    const float* x   = (const float*)d_in[0];   // [32, 512, 256]
    const float* mem = (const float*)d_in[1];   // [32, 4096, 256]
    float* out = (float*)d_out;

    float* invnx  = (float*)d_ws;               // 32*512
    float* invnm  = invnx + B_ * SX_;           // 32*4096
    float* rowmax = invnm + B_ * SM_;           // 32*4096

    invnorm_kernel<<<(B_ * SX_) / 4, 256, 0, stream>>>(x, invnx, B_ * SX_);
    invnorm_kernel<<<(B_ * SM_) / 4, 256, 0, stream>>>(mem, invnm, B_ * SM_);

    dim3 grid(SM_ / BM, B_);
    gemm_max_kernel<<<grid, 256, 0, stream>>>(x, mem, invnx, invnm, rowmax);

    top5_gather_kernel<<<B_, 256, 0, stream>>>(rowmax, mem, out);
}